// Round 5
// baseline (491.172 us; speedup 1.0000x reference)
//
#include <hip/hip_runtime.h>
#include <math.h>

// Problem constants (b=8, c=512, n=4096, 8 heads x 64)
#define NB 8
#define CDIM 512
#define NSEQ 4096
#define NHEAD 8
#define DHEAD 64
#define SCALE_Q 0.125f
#define SQRT_C  22.627416997969522f

typedef unsigned short u16;
typedef short bf16x8 __attribute__((ext_vector_type(8)));   // 8 bf16 = 4 VGPR
typedef float f32x4 __attribute__((ext_vector_type(4)));

// ---------------------------------------------------------------------------
// bf16 split helpers (round-to-nearest-even)
// ---------------------------------------------------------------------------
__device__ __forceinline__ u16 f2bf(float f) {
    unsigned u = __float_as_uint(f);
    u = u + 0x7FFFu + ((u >> 16) & 1u);
    return (u16)(u >> 16);
}
__device__ __forceinline__ float bf2f(u16 h) {
    return __uint_as_float(((unsigned)h) << 16);
}
__device__ __forceinline__ void split_bf(float v, u16& h, u16& l) {
    h = f2bf(v);
    l = f2bf(v - bf2f(h));
}

__device__ __forceinline__ void gload_lds16(const void* g, void* l) {
    __builtin_amdgcn_global_load_lds(
        (const __attribute__((address_space(1))) void*)g,
        (__attribute__((address_space(3))) void*)l, 16, 0, 0);
}

// ---------------------------------------------------------------------------
// Split-bf16 MFMA GEMM (NT): C[M,N] = (Ahi+Alo)[M,K] * (Bhi+Blo)[N,K]^T
// A row-major [M,K], B^T row-major [N,K], C row-major [M,N] fp32 (+row bias).
// 128x128 block tile, 4 waves (64x64 each), BK=32, mfma_f32_16x16x32_bf16,
// 3 products (hi*hi + hi*lo + lo*hi). LDS row = 128B = 8 slots of 16B
// (4 hi k-octets | 4 lo k-octets), slot XOR-swizzled by (row&7). Swizzle is
// applied on the global SOURCE side of global_load_lds (LDS dest stays
// linear: base + lane*16) and matched on the ds_read side (rule #21).
// ---------------------------------------------------------------------------
template<bool BIAS>
__global__ __launch_bounds__(256)
void gemm_split(const u16* __restrict__ Ahi, const u16* __restrict__ Alo,
                const u16* __restrict__ Bhi, const u16* __restrict__ Blo,
                float* __restrict__ C, const float* __restrict__ bias,
                int N, int K,
                long long sA, long long sB, long long sC)
{
    Ahi += (long long)blockIdx.z * sA; Alo += (long long)blockIdx.z * sA;
    Bhi += (long long)blockIdx.z * sB; Blo += (long long)blockIdx.z * sB;
    C   += (long long)blockIdx.z * sC;

    __shared__ __align__(16) char sb[32768];   // A 16KB | B 16KB

    const int tid = threadIdx.x;
    const int w = tid >> 6, lane = tid & 63;
    const int wr = w >> 1, wc = w & 1;
    const int row0 = blockIdx.y * 128, col0 = blockIdx.x * 128;

    // staging: lane writes LDS slot (lane&7) of row (lane>>3) in its chunk
    // (linear, HW-imposed); it must therefore LOAD global octet (slot^row).
    const int rsub = lane >> 3;              // row within an 8-row chunk
    const int jsel = (lane & 7) ^ rsub;      // global octet id (0-3 hi, 4-7 lo)
    const int koff = (jsel & 3) << 3;        // k offset in elements
    const u16* aops = (jsel < 4) ? Ahi : Alo;
    const u16* bops = (jsel < 4) ? Bhi : Blo;

    // fragment read offsets (constant across k-steps)
    const int r = lane & 15, h = lane >> 4;
    const int s_hi = (h ^ (r & 7)) << 4;
    const int s_lo = ((h + 4) ^ (r & 7)) << 4;
    int offA[4][2], offB[4][2];
#pragma unroll
    for (int i = 0; i < 4; ++i) {
        const int ra = (wr * 64 + i * 16 + r) * 128;
        offA[i][0] = ra + s_hi;  offA[i][1] = ra + s_lo;
        const int rb = 16384 + (wc * 64 + i * 16 + r) * 128;
        offB[i][0] = rb + s_hi;  offB[i][1] = rb + s_lo;
    }

    f32x4 acc[4][4];
#pragma unroll
    for (int i = 0; i < 4; ++i)
#pragma unroll
        for (int j = 0; j < 4; ++j) acc[i][j] = (f32x4){0.f, 0.f, 0.f, 0.f};

    for (int k0 = 0; k0 < K; k0 += 32) {
        __syncthreads();   // previous tile's reads complete before overwrite
#pragma unroll
        for (int i = 0; i < 4; ++i) {
            const int t = 4 * w + i;   // 8-row chunk index, 0..15
            gload_lds16(aops + (long long)(row0 + 8 * t + rsub) * K + k0 + koff,
                        sb + t * 1024);
            gload_lds16(bops + (long long)(col0 + 8 * t + rsub) * K + k0 + koff,
                        sb + 16384 + t * 1024);
        }
        __syncthreads();   // drains vmcnt: staged data visible

        bf16x8 ah[4], al[4], bh[4], bl[4];
#pragma unroll
        for (int i = 0; i < 4; ++i) {
            ah[i] = *(const bf16x8*)(sb + offA[i][0]);
            al[i] = *(const bf16x8*)(sb + offA[i][1]);
            bh[i] = *(const bf16x8*)(sb + offB[i][0]);
            bl[i] = *(const bf16x8*)(sb + offB[i][1]);
        }
#pragma unroll
        for (int mi = 0; mi < 4; ++mi)
#pragma unroll
            for (int ni = 0; ni < 4; ++ni) {
                acc[mi][ni] = __builtin_amdgcn_mfma_f32_16x16x32_bf16(ah[mi], bh[ni], acc[mi][ni], 0, 0, 0);
                acc[mi][ni] = __builtin_amdgcn_mfma_f32_16x16x32_bf16(ah[mi], bl[ni], acc[mi][ni], 0, 0, 0);
                acc[mi][ni] = __builtin_amdgcn_mfma_f32_16x16x32_bf16(al[mi], bh[ni], acc[mi][ni], 0, 0, 0);
            }
    }

    // epilogue: C/D layout col=lane&15, row=(lane>>4)*4+reg  [m89-verified]
#pragma unroll
    for (int mi = 0; mi < 4; ++mi) {
        const int rowm = row0 + wr * 64 + mi * 16 + h * 4;
#pragma unroll
        for (int ni = 0; ni < 4; ++ni) {
            const int coln = col0 + wc * 64 + ni * 16 + r;
#pragma unroll
            for (int reg = 0; reg < 4; ++reg) {
                float v = acc[mi][ni][reg];
                if (BIAS) v += bias[rowm + reg];
                C[(long long)(rowm + reg) * N + coln] = v;
            }
        }
    }
}

// ---------------------------------------------------------------------------
// Weight split: fp32 -> (hi, lo) bf16, same layout.
// ---------------------------------------------------------------------------
__global__ __launch_bounds__(256)
void cvt_split(const float* __restrict__ in, u16* __restrict__ hi,
               u16* __restrict__ lo, int n)
{
    for (int i = blockIdx.x * 256 + threadIdx.x; i < n; i += 65536) {
        u16 h, l; split_bf(in[i], h, l);
        hi[i] = h; lo[i] = l;
    }
}

// ---------------------------------------------------------------------------
// x [b][c][n] fp32 -> xT hi/lo bf16 [b][n][c]  (LDS 64x64 tile transpose)
// ---------------------------------------------------------------------------
__global__ __launch_bounds__(256)
void xpose_split(const float* __restrict__ x, u16* __restrict__ thi,
                 u16* __restrict__ tlo)
{
    __shared__ float t[64][65];
    const int tid = threadIdx.x;
    const int b = blockIdx.z, c0 = blockIdx.y * 64, n0 = blockIdx.x * 64;
    const float* xb = x + ((long long)b * CDIM + c0) * NSEQ + n0;
#pragma unroll
    for (int i = 0; i < 16; ++i) {
        const int f = tid + i * 256;
        t[f >> 6][f & 63] = xb[(long long)(f >> 6) * NSEQ + (f & 63)];
    }
    __syncthreads();
#pragma unroll
    for (int i = 0; i < 8; ++i) {
        const int f = tid + i * 256;
        const int nl = f >> 5, c2 = (f & 31) << 1;
        u16 h0, l0, h1, l1;
        split_bf(t[c2][nl], h0, l0);
        split_bf(t[c2 + 1][nl], h1, l1);
        const long long o = ((long long)b * NSEQ + n0 + nl) * CDIM + c0 + c2;
        ushort2 hv; hv.x = h0; hv.y = h1; *(ushort2*)&thi[o] = hv;
        ushort2 lv; lv.x = l0; lv.y = l1; *(ushort2*)&tlo[o] = lv;
    }
}

// ---------------------------------------------------------------------------
// k row stats: per row (b*512+o): max and 1/sum(exp(x-max)) over n=4096
// ---------------------------------------------------------------------------
__global__ __launch_bounds__(256)
void kstats_kernel(const float* __restrict__ k,
                   float* __restrict__ kmax, float* __restrict__ kinv)
{
    const long long row = blockIdx.x;
    const float* kr = k + row * (long long)NSEQ;
    const int tid = threadIdx.x;
    const int lane = tid & 63, wv = tid >> 6;

    float4 v[4];
    float m = -INFINITY;
#pragma unroll
    for (int i = 0; i < 4; ++i) {
        v[i] = ((const float4*)kr)[tid + i * 256];
        m = fmaxf(m, fmaxf(fmaxf(v[i].x, v[i].y), fmaxf(v[i].z, v[i].w)));
    }
#pragma unroll
    for (int off = 32; off; off >>= 1) m = fmaxf(m, __shfl_xor(m, off));

    __shared__ float red[8];
    if (lane == 0) red[wv] = m;
    __syncthreads();
    m = fmaxf(fmaxf(red[0], red[1]), fmaxf(red[2], red[3]));

    float s = 0.f;
#pragma unroll
    for (int i = 0; i < 4; ++i)
        s += __expf(v[i].x - m) + __expf(v[i].y - m)
           + __expf(v[i].z - m) + __expf(v[i].w - m);
#pragma unroll
    for (int off = 32; off; off >>= 1) s += __shfl_xor(s, off);
    if (lane == 0) red[4 + wv] = s;
    __syncthreads();
    if (tid == 0) {
        kmax[row] = m;
        kinv[row] = 1.0f / (red[4] + red[5] + red[6] + red[7]);
    }
}

// ---------------------------------------------------------------------------
// q softmax over d within head, *SCALE, emitted TRANSPOSED as split bf16:
// p^T [b][n][h*64+d]. Block = (ntile 64, h, b).
// ---------------------------------------------------------------------------
__global__ __launch_bounds__(256)
void qsoftmax_t(const float* __restrict__ q, u16* __restrict__ phi,
                u16* __restrict__ plo)
{
    __shared__ float t[64][65];     // [d][n]
    __shared__ float red[8][64];
    const int tid = threadIdx.x;
    const int n0 = blockIdx.x * 64, hh = blockIdx.y, b = blockIdx.z;
    const float* qb = q + ((long long)b * CDIM + hh * DHEAD) * NSEQ + n0;
#pragma unroll
    for (int i = 0; i < 16; ++i) {
        const int f = tid + i * 256;
        t[f >> 6][f & 63] = qb[(long long)(f >> 6) * NSEQ + (f & 63)];
    }
    __syncthreads();
    const int nl = tid & 63, part = tid >> 6;    // 4 threads per column
    float m = -INFINITY;
#pragma unroll
    for (int dd = 0; dd < 16; ++dd) m = fmaxf(m, t[part * 16 + dd][nl]);
    red[part][nl] = m;
    __syncthreads();
    m = fmaxf(fmaxf(red[0][nl], red[1][nl]), fmaxf(red[2][nl], red[3][nl]));
    float s = 0.f;
#pragma unroll
    for (int dd = 0; dd < 16; ++dd) {
        const float e = __expf(t[part * 16 + dd][nl] - m);
        t[part * 16 + dd][nl] = e;
        s += e;
    }
    red[4 + part][nl] = s;
    __syncthreads();
#pragma unroll
    for (int i = 0; i < 8; ++i) {
        const int f = tid + i * 256;
        const int n2 = f >> 5, c2 = (f & 31) << 1;
        const float inv = SCALE_Q / (red[4][n2] + red[5][n2] + red[6][n2] + red[7][n2]);
        u16 h0, l0, h1, l1;
        split_bf(t[c2][n2] * inv, h0, l0);
        split_bf(t[c2 + 1][n2] * inv, h1, l1);
        const long long o = ((long long)b * NSEQ + n0 + n2) * CDIM + hh * DHEAD + c2;
        ushort2 hv; hv.x = h0; hv.y = h1; *(ushort2*)&phi[o] = hv;
        ushort2 lv; lv.x = l0; lv.y = l1; *(ushort2*)&plo[o] = lv;
    }
}

// ---------------------------------------------------------------------------
// ctx_part[chunk][b,h,d,e] = sum over 512-col n-chunk of
//   softmax_n(k)[d,n] * v[e,n].   No atomics; reduced by ctx_reduce.
// ---------------------------------------------------------------------------
__global__ __launch_bounds__(256)
void ctx_part_kernel(const float* __restrict__ k, const float* __restrict__ v,
                     const float* __restrict__ kmax, const float* __restrict__ kinv,
                     float* __restrict__ ctx_part)
{
    const int chunk = blockIdx.x;        // 0..7
    const int bh = blockIdx.y;           // 0..63
    const int b = bh >> 3, h = bh & 7;

    __shared__ float kt[64 * 64];
    __shared__ float vt[64 * 64];

    const int tid = threadIdx.x;
    const int td = tid & 15, te = tid >> 4;
    const long long rowbase = (long long)b * CDIM + h * DHEAD;

    float acc[4][4];
#pragma unroll
    for (int i = 0; i < 4; ++i)
#pragma unroll
        for (int j = 0; j < 4; ++j) acc[i][j] = 0.f;

    for (int tile = 0; tile < 8; ++tile) {
        const int n0 = chunk * 512 + tile * 64;
        __syncthreads();
#pragma unroll
        for (int i = 0; i < 4; ++i) {
            const int f = tid + i * 256;
            const int row = f >> 4;
            const int c4 = (f & 15) << 2;
            const int cs = c4 ^ (((row >> 2) & 7) << 2);
            float4 kv = *(const float4*)&k[(rowbase + row) * (long long)NSEQ + n0 + c4];
            const float m_ = kmax[rowbase + row];
            const float s_ = kinv[rowbase + row];
            kv.x = __expf(kv.x - m_) * s_; kv.y = __expf(kv.y - m_) * s_;
            kv.z = __expf(kv.z - m_) * s_; kv.w = __expf(kv.w - m_) * s_;
            *(float4*)&kt[row * 64 + cs] = kv;
            *(float4*)&vt[row * 64 + cs] =
                *(const float4*)&v[(rowbase + row) * (long long)NSEQ + n0 + c4];
        }
        __syncthreads();

#pragma unroll
        for (int nn = 0; nn < 64; nn += 4) {
            float4 ka[4], vb[4];
#pragma unroll
            for (int i = 0; i < 4; ++i) {
                const int d = td * 4 + i;
                ka[i] = *(const float4*)&kt[d * 64 + (nn ^ (((d >> 2) & 7) << 2))];
            }
#pragma unroll
            for (int j = 0; j < 4; ++j) {
                const int e = te * 4 + j;
                vb[j] = *(const float4*)&vt[e * 64 + (nn ^ (((e >> 2) & 7) << 2))];
            }
#pragma unroll
            for (int i = 0; i < 4; ++i)
#pragma unroll
                for (int j = 0; j < 4; ++j) {
                    acc[i][j] = fmaf(ka[i].x, vb[j].x, acc[i][j]);
                    acc[i][j] = fmaf(ka[i].y, vb[j].y, acc[i][j]);
                    acc[i][j] = fmaf(ka[i].z, vb[j].z, acc[i][j]);
                    acc[i][j] = fmaf(ka[i].w, vb[j].w, acc[i][j]);
                }
        }
    }

    float* cbase = ctx_part + (long long)chunk * 262144 + ((long long)bh << 12);
#pragma unroll
    for (int i = 0; i < 4; ++i)
#pragma unroll
        for (int j = 0; j < 4; ++j)
            cbase[(td * 4 + i) * 64 + te * 4 + j] = acc[i][j];
}

__global__ __launch_bounds__(256)
void ctx_reduce(const float* __restrict__ part, float* __restrict__ ctx)
{
    const int i = blockIdx.x * 256 + threadIdx.x;   // grid 1024 -> 262144
    float s = 0.f;
#pragma unroll
    for (int c = 0; c < 8; ++c) s += part[(long long)c * 262144 + i];
    ctx[i] = s;
}

// ---------------------------------------------------------------------------
// W2[b][o][h*64+d] = sum_e Wout[o][h*64+e] * ctx[b][h][d][e] -> split bf16
// ---------------------------------------------------------------------------
__global__ __launch_bounds__(256)
void w2_split(const float* __restrict__ Wout, const float* __restrict__ ctx,
              u16* __restrict__ w2hi, u16* __restrict__ w2lo)
{
    const int o0 = blockIdx.x * 128;
    const int h = blockIdx.y, b = blockIdx.z;
    const int tid = threadIdx.x;

    __shared__ float ctxT[64 * 65];      // [e][d]
    __shared__ float WoutS[128 * 65];    // [o_local][e]

    const float* csrc = ctx + (((long long)b * NHEAD + h) << 12);
#pragma unroll
    for (int i = 0; i < 16; ++i) {
        const int f = tid + i * 256;
        ctxT[(f & 63) * 65 + (f >> 6)] = csrc[f];
    }
#pragma unroll
    for (int i = 0; i < 32; ++i) {
        const int f = tid + i * 256;
        WoutS[(f >> 6) * 65 + (f & 63)] =
            Wout[(long long)(o0 + (f >> 6)) * CDIM + h * DHEAD + (f & 63)];
    }
    __syncthreads();

    const int d = tid & 63, og = tid >> 6;
    float acc[32];
#pragma unroll
    for (int oo = 0; oo < 32; ++oo) acc[oo] = 0.f;

    for (int e = 0; e < 64; ++e) {
        const float c = ctxT[e * 65 + d];
#pragma unroll
        for (int oo = 0; oo < 32; ++oo)
            acc[oo] = fmaf(WoutS[(og * 32 + oo) * 65 + e], c, acc[oo]);
    }
#pragma unroll
    for (int oo = 0; oo < 32; ++oo) {
        const int o = o0 + og * 32 + oo;
        u16 hh, ll; split_bf(acc[oo], hh, ll);
        const long long idx = ((long long)b * CDIM + o) * CDIM + h * DHEAD + d;
        w2hi[idx] = hh; w2lo[idx] = ll;
    }
}

// ---------------------------------------------------------------------------
// RMSNorm over channel dim per (b, n): out = pre/max(||pre||,1e-12)*g*sqrt(512)
// ---------------------------------------------------------------------------
__global__ __launch_bounds__(256)
void rmsnorm_kernel(const float* __restrict__ pre, const float* __restrict__ g,
                    float* __restrict__ out)
{
    const int tid = threadIdx.x;
    const int b = blockIdx.y;
    const int n = blockIdx.x * 64 + (tid & 63);
    const int cg = tid >> 6;
    const float* pb = pre + (long long)b * CDIM * NSEQ + n;
    float* ob = out + (long long)b * CDIM * NSEQ + n;

    float ss = 0.f;
    for (int c = cg * 128; c < cg * 128 + 128; ++c) {
        const float x = pb[(long long)c * NSEQ];
        ss = fmaf(x, x, ss);
    }
    __shared__ float red[4][64];
    red[cg][tid & 63] = ss;
    __syncthreads();
    const float tot = red[0][tid & 63] + red[1][tid & 63]
                    + red[2][tid & 63] + red[3][tid & 63];
    const float rn = SQRT_C / fmaxf(sqrtf(tot), 1e-12f);

    for (int c = cg * 128; c < cg * 128 + 128; ++c)
        ob[(long long)c * NSEQ] = pb[(long long)c * NSEQ] * rn * g[c];
}

// ---------------------------------------------------------------------------
// Workspace layout (floats), lifetime-packed, total ~148 MB:
//   region A [0, QK)      : xT split (2xQK u16), later p^T split
//   region B [QK, 2QK)    : k -> q -> out_pre (serial reuse)
//   region C [2QK, ...)   : kmax | kinv | ctx | ctx_part(8x) | W splits | W2
//   v lives in d_out (exact size match), overwritten by final rmsnorm.
// WS guard: if ws_size is too small, launch NOTHING (clean validation fail
// instead of OOB crash -> decisive diagnostic for the round-2 core dump).
// ---------------------------------------------------------------------------
extern "C" void kernel_launch(void* const* d_in, const int* in_sizes, int n_in,
                              void* d_out, int out_size, void* d_ws, size_t ws_size,
                              hipStream_t stream)
{
    const float* x    = (const float*)d_in[0];
    const float* Wq   = (const float*)d_in[1];
    const float* Wk   = (const float*)d_in[2];
    const float* Wv   = (const float*)d_in[3];
    const float* Wout = (const float*)d_in[4];
    const float* bout = (const float*)d_in[5];
    const float* g    = (const float*)d_in[6];
    float* out = (float*)d_out;

    const long long PB = (long long)CDIM * NSEQ;     // 2,097,152
    const long long QK = (long long)NB * PB;         // 16,777,216

    // region C float count: 2*4096 + 262144 + 8*262144 + (22*262144 u16)/2
    const long long C_FLOATS = 8192 + 9LL * 262144 + 11LL * 262144;
    const size_t WS_NEEDED = (size_t)(2 * QK + C_FLOATS) * sizeof(float);
    if (ws_size < WS_NEEDED) return;   // constant across calls: capture-safe

    float* ws = (float*)d_ws;
    u16* xthi = (u16*)ws;                  // region A: QK u16
    u16* xtlo = xthi + QK;                 //           QK u16
    float* buf1 = ws + QK;                 // region B: QK floats
    float* kmax = ws + 2 * QK;             // region C
    float* kinv = kmax + 4096;
    float* ctx  = kinv + 4096;             // 262144
    float* ctxp = ctx + 262144;            // 8 x 262144
    u16* whi    = (u16*)(ctxp + 8 * 262144);   // 3 x 262144 u16
    u16* wlo    = whi + 3 * 262144;
    u16* w2hi   = wlo + 3 * 262144;        // 8 x 262144 u16
    u16* w2lo   = w2hi + (long long)NB * 262144;

    float* kbuf = buf1;                    // phase 1
    float* vbuf = out;                     // d_out as scratch for v
    float* qbuf = buf1;                    // phase 2 (k dead)
    float* outpre = buf1;                  // phase 3 (q dead)
    u16* phi = xthi;                       // p^T reuses xT (dead after GEMM q)
    u16* plo = xtlo;

    // weight + input splits
    cvt_split<<<256, 256, 0, stream>>>(Wq, whi,              wlo,              262144);
    cvt_split<<<256, 256, 0, stream>>>(Wk, whi + 262144,     wlo + 262144,     262144);
    cvt_split<<<256, 256, 0, stream>>>(Wv, whi + 2 * 262144, wlo + 2 * 262144, 262144);
    xpose_split<<<dim3(64, 8, 8), 256, 0, stream>>>(x, xthi, xtlo);

    const dim3 gg(NSEQ / 128, CDIM / 128, NB);   // (32, 4, 8)

    // k first, then v, ctx; q last among xT consumers (so xT can be reused)
    gemm_split<false><<<gg, 256, 0, stream>>>(whi + 262144, wlo + 262144,
                                              xthi, xtlo, kbuf, nullptr,
                                              NSEQ, CDIM, 0, PB, PB);
    kstats_kernel<<<dim3(NB * CDIM), 256, 0, stream>>>(kbuf, kmax, kinv);

    gemm_split<false><<<gg, 256, 0, stream>>>(whi + 2 * 262144, wlo + 2 * 262144,
                                              xthi, xtlo, vbuf, nullptr,
                                              NSEQ, CDIM, 0, PB, PB);
    ctx_part_kernel<<<dim3(8, NB * NHEAD), 256, 0, stream>>>(kbuf, vbuf, kmax, kinv, ctxp);
    ctx_reduce<<<1024, 256, 0, stream>>>(ctxp, ctx);

    gemm_split<false><<<gg, 256, 0, stream>>>(whi, wlo,
                                              xthi, xtlo, qbuf, nullptr,
                                              NSEQ, CDIM, 0, PB, PB);
    qsoftmax_t<<<dim3(NSEQ / 64, NHEAD, NB), 256, 0, stream>>>(qbuf, phi, plo);

    w2_split<<<dim3(4, NHEAD, NB), 256, 0, stream>>>(Wout, ctx, w2hi, w2lo);
    gemm_split<true><<<gg, 256, 0, stream>>>(w2hi, w2lo, phi, plo, outpre, bout,
                                             NSEQ, CDIM, 262144, PB, PB);

    rmsnorm_kernel<<<dim3(NSEQ / 64, NB), 256, 0, stream>>>(outpre, g, out);
}